// Round 10
// baseline (359.655 us; speedup 1.0000x reference)
//
#include <hip/hip_runtime.h>

#define NN 20000
#define NE 320000
#define EP (NE + NN)          // 340000 edges incl. self loops
#define NG 8
#define HC 256
#define NODE_IN 18
#define HID 64
#define NEG_SLOPE 0.2f
#define BN_EPS 1e-5f

// ---------------- workspace layout (float offsets) ----------------
#define OFF_XL    0u                      // bf16 [NN*256]; also rank[NE] during CSR build
#define OFF_XR    5120000u                // fp32 [NN*256]
#define OFF_H1    10240000u               // bf16 [NN*256] -> ends at 12800000
#define OFF_WTL   12800000u               // bf16 [256*256] n-major (g2_wl^T)
#define OFF_WTR   12832768u               // bf16 [256*256] n-major (g2_wr^T)
#define OFF_H0    15360000u               // fp32 [NN*64]  (h0, later reused as h2)
#define OFF_H3    16640000u               // fp32 [NN*64]
#define OFF_ZERO  18000000u               // start of zeroed region
#define OFF_CNT   18000000u               // uint cnt [NN]
#define OFF_PSUM  18020000u               // [8*64]
#define OFF_PMAX  18020512u               // [8*64]
#define OFF_PCNT  18021024u               // [16]
#define ZERO_FLOATS (18021040u - 18000000u)
#define OFF_EACSR 18021040u               // [EP*4] CSR-ordered edge attrs
#define OFF_RP    19381040u               // int [NN+1]
#define OFF_SRC   19421041u               // int [EP] (self-loop = LAST slot of row, sign bit)
#define OFF_BSUM  19761056u               // int [32]

#define SCAN_ELEM 1024
#define SCAN_NB ((NN + SCAN_ELEM - 1) / SCAN_ELEM)   // 20

typedef __attribute__((ext_vector_type(8))) short bf16x8_t;
typedef __attribute__((ext_vector_type(4))) float f32x4_t;

__device__ __forceinline__ ushort f2bf(float f) {   // RNE float->bf16
  unsigned u = __float_as_uint(f);
  unsigned r = (u + 0x7fffu + ((u >> 16) & 1u)) >> 16;
  return (ushort)r;
}
__device__ __forceinline__ float bf2f(ushort b) {
  return __uint_as_float(((unsigned)b) << 16);
}

// ------------------------------------------------------------------
// K1: per-dst edge count; returned old value = rank within dst row.
__global__ __launch_bounds__(256) void k_count(
    const int* __restrict__ ei, unsigned* __restrict__ cnt, int* __restrict__ rank) {
  int e = blockIdx.x * 256 + threadIdx.x;
  if (e >= NE) return;
  int d = ei[NE + e];
  rank[e] = (int)atomicAdd(&cnt[d], 1u);
}

// ------------------------------------------------------------------
// K_cast_wt: W[k][n] fp32 -> Wt[n][k] bf16 (both g2 weight matrices)
__global__ __launch_bounds__(256) void k_cast_wt(
    const float* __restrict__ Wl, const float* __restrict__ Wr,
    ushort* __restrict__ WtL, ushort* __restrict__ WtR) {
  int b = blockIdx.x;
  const float* W = (b < 256) ? Wl : Wr;
  ushort* Wt = (b < 256) ? WtL : WtR;
  int k = b & 255;
  int n = threadIdx.x;
  Wt[n * 256 + k] = f2bf(W[k * 256 + n]);
}

// ------------------------------------------------------------------
// K3: encoder, wave-per-node (lane = channel).
#define ENC_NPW 4
__global__ __launch_bounds__(256) void k_encoder(
    const float* __restrict__ x, const float* __restrict__ w1, const float* __restrict__ b1,
    const float* __restrict__ w2, const float* __restrict__ b2, float* __restrict__ h0) {
  __shared__ float W1[NODE_IN * HID];
  __shared__ float W2[HID * HID];
  __shared__ float B1s[HID];
  __shared__ float B2s[HID];
  __shared__ float hid_s[4][HID];
  const int tid = threadIdx.x;
  for (int i = tid; i < NODE_IN * HID; i += 256) W1[i] = w1[i];
  for (int i = tid; i < HID * HID; i += 256) W2[i] = w2[i];
  if (tid < HID) { B1s[tid] = b1[tid]; B2s[tid] = b2[tid]; }
  __syncthreads();
  const int lane = tid & 63;
  const int w = tid >> 6;
  #pragma unroll
  for (int t = 0; t < ENC_NPW; t++) {
    const int n = blockIdx.x * (4 * ENC_NPW) + w * ENC_NPW + t;
    const float* xp = &x[(size_t)n * NODE_IN];
    float s = B1s[lane];
    #pragma unroll
    for (int i = 0; i < NODE_IN; i++) s += xp[i] * W1[i * HID + lane];
    hid_s[w][lane] = fmaxf(s, 0.f);
    float o = B2s[lane];
    #pragma unroll 8
    for (int k = 0; k < HID; k++) o += hid_s[w][k] * W2[k * HID + lane];
    h0[(size_t)n * HID + lane] = o;
  }
}

// ------------------------------------------------------------------
__global__ __launch_bounds__(256) void k_scan_blk(
    const unsigned* __restrict__ cnt, int* __restrict__ row_ptr, int* __restrict__ bsums) {
  __shared__ int wsum[4];
  const int tid = threadIdx.x, lane = tid & 63, w = tid >> 6;
  const int i0 = blockIdx.x * SCAN_ELEM + tid * 4;
  int v0 = (i0 + 0 < NN) ? ((int)cnt[i0 + 0] + 1) : 0;
  int v1 = (i0 + 1 < NN) ? ((int)cnt[i0 + 1] + 1) : 0;
  int v2 = (i0 + 2 < NN) ? ((int)cnt[i0 + 2] + 1) : 0;
  int v3 = (i0 + 3 < NN) ? ((int)cnt[i0 + 3] + 1) : 0;
  int tsum = v0 + v1 + v2 + v3;
  int incl = tsum;
  #pragma unroll
  for (int off = 1; off < 64; off <<= 1) {
    int t = __shfl_up(incl, off);
    if (lane >= off) incl += t;
  }
  if (lane == 63) wsum[w] = incl;
  __syncthreads();
  int p = incl - tsum;
  #pragma unroll
  for (int k = 0; k < 4; k++) if (k < w) p += wsum[k];
  if (i0 + 0 < NN) row_ptr[i0 + 0] = p;
  if (i0 + 1 < NN) row_ptr[i0 + 1] = p + v0;
  if (i0 + 2 < NN) row_ptr[i0 + 2] = p + v0 + v1;
  if (i0 + 3 < NN) row_ptr[i0 + 3] = p + v0 + v1 + v2;
  if (tid == 0) bsums[blockIdx.x] = wsum[0] + wsum[1] + wsum[2] + wsum[3];
}

__global__ __launch_bounds__(256) void k_scan_add(
    const int* __restrict__ bsums, int* __restrict__ row_ptr) {
  const int b = blockIdx.x, tid = threadIdx.x;
  int off = 0;
  for (int j = 0; j < b; j++) off += bsums[j];
  const int i0 = b * SCAN_ELEM + tid * 4;
  #pragma unroll
  for (int k = 0; k < 4; k++) {
    int i = i0 + k;
    if (i < NN) row_ptr[i] += off;
  }
  if (b == 0 && tid == 0) row_ptr[NN] = EP;
}

__global__ __launch_bounds__(256) void k_csr_scatter(
    const int* __restrict__ ei, const int* __restrict__ rank,
    const int* __restrict__ row_ptr, const float* __restrict__ ea,
    int* __restrict__ srcs, float* __restrict__ ea_csr) {
  int e = blockIdx.x * 256 + threadIdx.x;
  if (e >= NE) return;
  int s = ei[e], d = ei[NE + e];
  int p = row_ptr[d] + rank[e];
  srcs[p] = s;
  *(float4*)&ea_csr[(size_t)p * 4] = *(const float4*)&ea[(size_t)e * 4];
}

__global__ __launch_bounds__(256) void k_loop_row(
    const int* __restrict__ row_ptr, int* __restrict__ srcs, float* __restrict__ ea_csr) {
  int i = blockIdx.x * 256 + threadIdx.x;
  if (i >= NN) return;
  int start = row_ptr[i], last = row_ptr[i + 1] - 1;
  float sx = 0.f, sy = 0.f, sz = 0.f, sw = 0.f;
  for (int j = start; j < last; ++j) {
    float4 a = *(const float4*)&ea_csr[(size_t)j * 4];
    sx += a.x; sy += a.y; sz += a.z; sw += a.w;
  }
  float c = (float)(last - start);
  if (c < 1.f) c = 1.f;
  float rc = 1.f / c;
  float4 o = {sx * rc, sy * rc, sz * rc, sw * rc};
  *(float4*)&ea_csr[(size_t)last * 4] = o;
  srcs[last] = i | (int)0x80000000;
}

// ------------------------------------------------------------------
// K4: fp32 vector GEMM (layer-1, K=64): OUT[NN][256] = A[NN][K]@W[K][256]
template <int K, int OBF>
__global__ __launch_bounds__(256) void k_gemm256(
    const float* __restrict__ A, const float* __restrict__ W, void* __restrict__ OUTv) {
  __shared__ float Wl[32 * 256];
  __shared__ float Al[32 * 36];
  const int tid = threadIdx.x;
  const int n0 = blockIdx.x * 32;
  const int tx = tid & 63, ty = tid >> 6;
  float acc[8][4];
  #pragma unroll
  for (int m = 0; m < 8; m++)
    #pragma unroll
    for (int c = 0; c < 4; c++) acc[m][c] = 0.f;

  for (int kt = 0; kt < K; kt += 32) {
    #pragma unroll
    for (int r = 0; r < 8; r++) {
      int i4 = tid + 256 * r;
      int row = i4 >> 6;
      int col4 = (i4 & 63) * 4;
      *(float4*)&Wl[row * 256 + col4] = *(const float4*)&W[(size_t)(kt + row) * 256 + col4];
    }
    {
      int m = tid >> 3, kk = (tid & 7) * 4;
      float4 av = *(const float4*)&A[(size_t)(n0 + m) * K + kt + kk];
      Al[(kk + 0) * 36 + m] = av.x;
      Al[(kk + 1) * 36 + m] = av.y;
      Al[(kk + 2) * 36 + m] = av.z;
      Al[(kk + 3) * 36 + m] = av.w;
    }
    __syncthreads();
    #pragma unroll 8
    for (int k = 0; k < 32; k++) {
      float4 b = *(float4*)&Wl[k * 256 + tx * 4];
      float4 a0v = *(float4*)&Al[k * 36 + ty * 8];
      float4 a1v = *(float4*)&Al[k * 36 + ty * 8 + 4];
      float am[8] = {a0v.x, a0v.y, a0v.z, a0v.w, a1v.x, a1v.y, a1v.z, a1v.w};
      #pragma unroll
      for (int m = 0; m < 8; m++) {
        acc[m][0] += am[m] * b.x;
        acc[m][1] += am[m] * b.y;
        acc[m][2] += am[m] * b.z;
        acc[m][3] += am[m] * b.w;
      }
    }
    __syncthreads();
  }
  if (OBF) {
    ushort* OUT = (ushort*)OUTv;
    #pragma unroll
    for (int m = 0; m < 8; m++) {
      ushort4 o = {f2bf(acc[m][0]), f2bf(acc[m][1]), f2bf(acc[m][2]), f2bf(acc[m][3])};
      *(ushort4*)&OUT[(size_t)(n0 + ty * 8 + m) * 256 + tx * 4] = o;
    }
  } else {
    float* OUT = (float*)OUTv;
    #pragma unroll
    for (int m = 0; m < 8; m++) {
      float4 o = {acc[m][0], acc[m][1], acc[m][2], acc[m][3]};
      *(float4*)&OUT[(size_t)(n0 + ty * 8 + m) * 256 + tx * 4] = o;
    }
  }
}

// ------------------------------------------------------------------
// K4b: MFMA bf16 GEMM (layer-2, K=256): OUT[NN][256] = A[NN][256] @ W[256][256]
template <int OBF>
__global__ __launch_bounds__(256) void k_gemm_mfma(
    const ushort* __restrict__ A, const ushort* __restrict__ Wt, void* __restrict__ OUTv) {
  __shared__ ushort Asub[32][72];
  __shared__ ushort Wsub[256][72];
  const int tid = threadIdx.x;
  const int lane = tid & 63;
  const int w = tid >> 6;
  const int n0 = blockIdx.x * 32;
  const int lr = lane & 15;
  const int lk = (lane >> 4) * 8;

  f32x4_t acc[2][4];
  #pragma unroll
  for (int m = 0; m < 2; m++)
    #pragma unroll
    for (int n = 0; n < 4; n++) acc[m][n] = (f32x4_t){0.f, 0.f, 0.f, 0.f};

  for (int kt = 0; kt < 256; kt += 64) {
    {
      int r = tid >> 3, seg = (tid & 7) * 8;
      *(uint4*)&Asub[r][seg] = *(const uint4*)&A[(size_t)(n0 + r) * 256 + kt + seg];
    }
    #pragma unroll
    for (int rep = 0; rep < 8; rep++) {
      int idx = rep * 256 + tid;
      int r = idx >> 3, seg = (idx & 7) * 8;
      *(uint4*)&Wsub[r][seg] = *(const uint4*)&Wt[(size_t)r * 256 + kt + seg];
    }
    __syncthreads();
    #pragma unroll
    for (int kk = 0; kk < 2; kk++) {
      bf16x8_t af0 = *(bf16x8_t*)&Asub[lr][kk * 32 + lk];
      bf16x8_t af1 = *(bf16x8_t*)&Asub[16 + lr][kk * 32 + lk];
      #pragma unroll
      for (int n = 0; n < 4; n++) {
        bf16x8_t bfr = *(bf16x8_t*)&Wsub[w * 64 + n * 16 + lr][kk * 32 + lk];
        acc[0][n] = __builtin_amdgcn_mfma_f32_16x16x32_bf16(af0, bfr, acc[0][n], 0, 0, 0);
        acc[1][n] = __builtin_amdgcn_mfma_f32_16x16x32_bf16(af1, bfr, acc[1][n], 0, 0, 0);
      }
    }
    __syncthreads();
  }
  const int crow = (lane >> 4) * 4;
  #pragma unroll
  for (int m = 0; m < 2; m++) {
    #pragma unroll
    for (int n = 0; n < 4; n++) {
      int col = w * 64 + n * 16 + lr;
      #pragma unroll
      for (int r = 0; r < 4; r++) {
        int row = n0 + m * 16 + crow + r;
        if (OBF) ((ushort*)OUTv)[(size_t)row * 256 + col] = f2bf(acc[m][n][r]);
        else     ((float*)OUTv)[(size_t)row * 256 + col] = acc[m][n][r];
      }
    }
  }
}

// ------------------------------------------------------------------
// Per-edge GAT compute body (direct exp, stream accumulators by reference)
__device__ __forceinline__ void gat_edge(
    float4 a, float xx, float xy, float xz, float xw,
    const float4& xrd, const float4& we0, const float4& we1,
    const float4& we2, const float4& we3, const float4& attv,
    float& dn, float& c0, float& c1, float& c2, float& c3) {
  float m0 = xx + xrd.x + a.x * we0.x + a.y * we1.x + a.z * we2.x + a.w * we3.x;
  float m1 = xy + xrd.y + a.x * we0.y + a.y * we1.y + a.z * we2.y + a.w * we3.y;
  float m2 = xz + xrd.z + a.x * we0.z + a.y * we1.z + a.z * we2.z + a.w * we3.z;
  float m3 = xw + xrd.w + a.x * we0.w + a.y * we1.w + a.z * we2.w + a.w * we3.w;
  m0 = fmaxf(m0, NEG_SLOPE * m0);
  m1 = fmaxf(m1, NEG_SLOPE * m1);
  m2 = fmaxf(m2, NEG_SLOPE * m2);
  m3 = fmaxf(m3, NEG_SLOPE * m3);
  float lg = m0 * attv.x + m1 * attv.y + m2 * attv.z + m3 * attv.w;
  lg += __shfl_xor(lg, 1);
  lg += __shfl_xor(lg, 2);
  lg += __shfl_xor(lg, 4);
  lg += __shfl_xor(lg, 8);
  float p = __expf(lg);
  dn += p;
  c0 = fmaf(p, xx, c0);
  c1 = fmaf(p, xy, c1);
  c2 = fmaf(p, xz, c2);
  c3 = fmaf(p, xw, c3);
}

// K5: fused GATv2 — round-6 loop structure (2-edge unroll, dual A/B
// streams, NO prefetch) + direct-exp softmax.
template <int CONCAT>
__global__ __launch_bounds__(256) void k_gat_fused(
    const ushort* __restrict__ xl, const float* __restrict__ xr,
    const float* __restrict__ we, const float* __restrict__ att,
    const int* __restrict__ srcs, const float* __restrict__ ea_csr,
    const int* __restrict__ row_ptr,
    const float* __restrict__ bias, const float* __restrict__ bng,
    const float* __restrict__ bnb, void* __restrict__ outp) {
  const int lane = threadIdx.x & 63;
  const int w = threadIdx.x >> 6;
  const int i = blockIdx.x * 4 + w;
  const int c0 = lane * 4;

  const float4 attv = *(const float4*)&att[c0];
  const float4 we0 = *(const float4*)&we[0 * HC + c0];
  const float4 we1 = *(const float4*)&we[1 * HC + c0];
  const float4 we2 = *(const float4*)&we[2 * HC + c0];
  const float4 we3 = *(const float4*)&we[3 * HC + c0];
  const float4 xrd = *(const float4*)&xr[(size_t)i * HC + c0];

  const int start = row_ptr[i];
  const int deg = row_ptr[i + 1] - start;

  float dnA = 0.f, aA0 = 0.f, aA1 = 0.f, aA2 = 0.f, aA3 = 0.f;
  float dnB = 0.f, aB0 = 0.f, aB1 = 0.f, aB2 = 0.f, aB3 = 0.f;

  for (int base = 0; base < deg; base += 64) {
    int rem = deg - base;
    if (rem > 64) rem = 64;
    int sv = 0;
    if (lane < rem) sv = srcs[start + base + lane];
    int jj = 0;
    for (; jj + 2 <= rem; jj += 2) {
      int s0 = __shfl(sv, jj) & 0x7fffffff;
      int s1 = __shfl(sv, jj + 1) & 0x7fffffff;
      float4 a0 = *(const float4*)&ea_csr[(size_t)(start + base + jj) * 4];
      float4 a1 = *(const float4*)&ea_csr[(size_t)(start + base + jj + 1) * 4];
      ushort4 u0 = *(const ushort4*)&xl[(size_t)s0 * HC + c0];
      ushort4 u1 = *(const ushort4*)&xl[(size_t)s1 * HC + c0];
      gat_edge(a0, bf2f(u0.x), bf2f(u0.y), bf2f(u0.z), bf2f(u0.w),
               xrd, we0, we1, we2, we3, attv, dnA, aA0, aA1, aA2, aA3);
      gat_edge(a1, bf2f(u1.x), bf2f(u1.y), bf2f(u1.z), bf2f(u1.w),
               xrd, we0, we1, we2, we3, attv, dnB, aB0, aB1, aB2, aB3);
    }
    if (jj < rem) {   // tail edge -> stream A
      int s0 = __shfl(sv, jj) & 0x7fffffff;
      float4 a0 = *(const float4*)&ea_csr[(size_t)(start + base + jj) * 4];
      ushort4 u0 = *(const ushort4*)&xl[(size_t)s0 * HC + c0];
      gat_edge(a0, bf2f(u0.x), bf2f(u0.y), bf2f(u0.z), bf2f(u0.w),
               xrd, we0, we1, we2, we3, attv, dnA, aA0, aA1, aA2, aA3);
    }
  }

  float rinv = 1.f / (dnA + dnB);
  float acc0 = (aA0 + aB0) * rinv;
  float acc1 = (aA1 + aB1) * rinv;
  float acc2 = (aA2 + aB2) * rinv;
  float acc3 = (aA3 + aB3) * rinv;

  const float inv_sqrt = rsqrtf(1.f + BN_EPS);
  if (CONCAT) {
    float4 bi = *(const float4*)&bias[c0];
    float4 g = *(const float4*)&bng[c0];
    float4 bb = *(const float4*)&bnb[c0];
    float v0 = (acc0 + bi.x) * (g.x * inv_sqrt) + bb.x;
    float v1 = (acc1 + bi.y) * (g.y * inv_sqrt) + bb.y;
    float v2 = (acc2 + bi.z) * (g.z * inv_sqrt) + bb.z;
    float v3 = (acc3 + bi.w) * (g.w * inv_sqrt) + bb.w;
    v0 = (v0 > 0.f) ? v0 : (__expf(v0) - 1.f);
    v1 = (v1 > 0.f) ? v1 : (__expf(v1) - 1.f);
    v2 = (v2 > 0.f) ? v2 : (__expf(v2) - 1.f);
    v3 = (v3 > 0.f) ? v3 : (__expf(v3) - 1.f);
    ushort* op = (ushort*)outp;                      // h1 stored bf16 for MFMA
    ushort4 o = {f2bf(v0), f2bf(v1), f2bf(v2), f2bf(v3)};
    *(ushort4*)&op[(size_t)i * HC + c0] = o;
  } else {
    acc0 += __shfl_xor(acc0, 16); acc0 += __shfl_xor(acc0, 32);
    acc1 += __shfl_xor(acc1, 16); acc1 += __shfl_xor(acc1, 32);
    acc2 += __shfl_xor(acc2, 16); acc2 += __shfl_xor(acc2, 32);
    acc3 += __shfl_xor(acc3, 16); acc3 += __shfl_xor(acc3, 32);
    if (lane < 16) {
      int cc = lane * 4;
      float4 bi = *(const float4*)&bias[cc];
      float4 g = *(const float4*)&bng[cc];
      float4 bb = *(const float4*)&bnb[cc];
      float v0 = (0.25f * acc0 + bi.x) * (g.x * inv_sqrt) + bb.x;
      float v1 = (0.25f * acc1 + bi.y) * (g.y * inv_sqrt) + bb.y;
      float v2 = (0.25f * acc2 + bi.z) * (g.z * inv_sqrt) + bb.z;
      float v3 = (0.25f * acc3 + bi.w) * (g.w * inv_sqrt) + bb.w;
      v0 = (v0 > 0.f) ? v0 : (__expf(v0) - 1.f);
      v1 = (v1 > 0.f) ? v1 : (__expf(v1) - 1.f);
      v2 = (v2 > 0.f) ? v2 : (__expf(v2) - 1.f);
      v3 = (v3 > 0.f) ? v3 : (__expf(v3) - 1.f);
      float* op = (float*)outp;
      float4 o = {v0, v1, v2, v3};
      *(float4*)&op[(size_t)i * 64 + cc] = o;
    }
  }
}

// ------------------------------------------------------------------
// K8: fused SAGE, prefetched srcs + 4 independent streams.
__global__ __launch_bounds__(256) void k_sage(
    const float* __restrict__ h2, const int* __restrict__ row_ptr,
    const int* __restrict__ srcs, const unsigned* __restrict__ cnt,
    const float* __restrict__ wl, const float* __restrict__ bl,
    const float* __restrict__ wr, const float* __restrict__ bng,
    const float* __restrict__ bnb, float* __restrict__ h3) {
  __shared__ float agg_s[4][64];
  __shared__ float h2_s[4][64];
  int lane = threadIdx.x & 63;
  int w = threadIdx.x >> 6;
  int i = blockIdx.x * 4 + w;
  int start = row_ptr[i];
  int nreal = row_ptr[i + 1] - 1 - start;
  float a0 = 0.f, a1 = 0.f, a2 = 0.f, a3 = 0.f;
  for (int base = 0; base < nreal; base += 64) {
    int rem = nreal - base;
    if (rem > 64) rem = 64;
    int sv = 0;
    if (lane < rem) sv = srcs[start + base + lane];
    int jj = 0;
    for (; jj + 4 <= rem; jj += 4) {
      int s0 = __shfl(sv, jj);
      int s1 = __shfl(sv, jj + 1);
      int s2 = __shfl(sv, jj + 2);
      int s3 = __shfl(sv, jj + 3);
      a0 += h2[(size_t)s0 * 64 + lane];
      a1 += h2[(size_t)s1 * 64 + lane];
      a2 += h2[(size_t)s2 * 64 + lane];
      a3 += h2[(size_t)s3 * 64 + lane];
    }
    for (; jj < rem; ++jj) {
      int s0 = __shfl(sv, jj);
      a0 += h2[(size_t)s0 * 64 + lane];
    }
  }
  float a = (a0 + a1) + (a2 + a3);
  float c = (float)cnt[i];
  if (c < 1.f) c = 1.f;
  agg_s[w][lane] = a / c;
  h2_s[w][lane] = h2[(size_t)i * 64 + lane];
  __syncthreads();
  float s = bl[lane];
  #pragma unroll 4
  for (int k = 0; k < 64; k++)
    s += agg_s[w][k] * wl[k * 64 + lane] + h2_s[w][k] * wr[k * 64 + lane];
  s = s * (bng[lane] * rsqrtf(1.f + BN_EPS)) + bnb[lane];
  s = fmaxf(s, 0.f);
  h3[(size_t)i * 64 + lane] = s;
}

// ------------------------------------------------------------------
__global__ __launch_bounds__(256) void k_pool(
    const float* __restrict__ h3, const int* __restrict__ batch,
    float* __restrict__ psum, float* __restrict__ pmax, float* __restrict__ pcnt) {
  int j = threadIdx.x & 63, grp = threadIdx.x >> 6;
  int nbase = blockIdx.x * 256 + grp * 64;
  float s = 0.f, m = 0.f, cn = 0.f;
  int cur = -1;
  for (int t = 0; t < 64; t++) {
    int n = nbase + t;
    if (n >= NN) break;
    int g = batch[n];
    if (g != cur) {
      if (cur >= 0) {
        atomicAdd(&psum[cur * 64 + j], s);
        atomicMax((int*)&pmax[cur * 64 + j], __float_as_int(m));
        if (j == 0) atomicAdd(&pcnt[cur], cn);
      }
      cur = g; s = 0.f; m = 0.f; cn = 0.f;
    }
    float v = h3[(size_t)n * 64 + j];
    s += v; m = fmaxf(m, v); cn += 1.f;
  }
  if (cur >= 0) {
    atomicAdd(&psum[cur * 64 + j], s);
    atomicMax((int*)&pmax[cur * 64 + j], __float_as_int(m));
    if (j == 0) atomicAdd(&pcnt[cur], cn);
  }
}

// ------------------------------------------------------------------
__global__ void k_graph_head(
    const float* __restrict__ psum, const float* __restrict__ pmax,
    const float* __restrict__ pcnt,
    const float* __restrict__ w1, const float* __restrict__ b1,
    const float* __restrict__ w2, const float* __restrict__ b2,
    const float* __restrict__ w3, const float* __restrict__ b3,
    float* __restrict__ out) {
  __shared__ float hp[128];
  __shared__ float z1[64];
  __shared__ float z2[32];
  int g = blockIdx.x, j = threadIdx.x;
  float c = pcnt[g];
  if (c < 1.f) c = 1.f;
  hp[j] = psum[g * 64 + j] / c;
  hp[64 + j] = pmax[g * 64 + j];
  __syncthreads();
  float s = b1[j];
  #pragma unroll 8
  for (int k = 0; k < 128; k++) s += hp[k] * w1[k * 64 + j];
  z1[j] = fmaxf(s, 0.f);
  __syncthreads();
  if (j < 32) {
    float s2 = b2[j];
    #pragma unroll 8
    for (int k = 0; k < 64; k++) s2 += z1[k] * w2[k * 32 + j];
    z2[j] = fmaxf(s2, 0.f);
  }
  __syncthreads();
  if (j == 0) {
    float s3 = b3[0];
    #pragma unroll
    for (int k = 0; k < 32; k++) s3 += z2[k] * w3[k];
    out[g] = 1.f / (1.f + expf(-s3));
  }
}

// ------------------------------------------------------------------
__global__ __launch_bounds__(256) void k_edge_head(
    const float* __restrict__ h3, const int* __restrict__ ei,
    const float* __restrict__ ea,
    const float* __restrict__ w1, const float* __restrict__ b1,
    const float* __restrict__ w2, const float* __restrict__ b2,
    float* __restrict__ out) {
  int e = blockIdx.x * 256 + threadIdx.x;
  if (e >= NE) return;
  int s = ei[e], d = ei[NE + e];
  float acc[32];
  #pragma unroll
  for (int j = 0; j < 32; j++) acc[j] = b1[j];
  const float4* hs = (const float4*)&h3[(size_t)s * 64];
  const float4* hd = (const float4*)&h3[(size_t)d * 64];
  for (int k4 = 0; k4 < 16; k4++) {
    float4 v = hs[k4];
    const float* w = &w1[k4 * 4 * 32];
    #pragma unroll
    for (int j = 0; j < 32; j++) acc[j] += v.x * w[j];
    #pragma unroll
    for (int j = 0; j < 32; j++) acc[j] += v.y * w[32 + j];
    #pragma unroll
    for (int j = 0; j < 32; j++) acc[j] += v.z * w[64 + j];
    #pragma unroll
    for (int j = 0; j < 32; j++) acc[j] += v.w * w[96 + j];
  }
  for (int k4 = 0; k4 < 16; k4++) {
    float4 v = hd[k4];
    const float* w = &w1[(64 + k4 * 4) * 32];
    #pragma unroll
    for (int j = 0; j < 32; j++) acc[j] += v.x * w[j];
    #pragma unroll
    for (int j = 0; j < 32; j++) acc[j] += v.y * w[32 + j];
    #pragma unroll
    for (int j = 0; j < 32; j++) acc[j] += v.z * w[64 + j];
    #pragma unroll
    for (int j = 0; j < 32; j++) acc[j] += v.w * w[96 + j];
  }
  {
    float4 v = *(const float4*)&ea[(size_t)e * 4];
    const float* w = &w1[128 * 32];
    #pragma unroll
    for (int j = 0; j < 32; j++) acc[j] += v.x * w[j];
    #pragma unroll
    for (int j = 0; j < 32; j++) acc[j] += v.y * w[32 + j];
    #pragma unroll
    for (int j = 0; j < 32; j++) acc[j] += v.z * w[64 + j];
    #pragma unroll
    for (int j = 0; j < 32; j++) acc[j] += v.w * w[96 + j];
  }
  float s2 = b2[0];
  #pragma unroll
  for (int j = 0; j < 32; j++) s2 += fmaxf(acc[j], 0.f) * w2[j];
  out[e] = 1.f / (1.f + expf(-s2));
}

// ------------------------------------------------------------------
extern "C" void kernel_launch(void* const* d_in, const int* in_sizes, int n_in,
                              void* d_out, int out_size, void* d_ws, size_t ws_size,
                              hipStream_t stream) {
  const float* x         = (const float*)d_in[0];
  const float* edge_attr = (const float*)d_in[1];
  const float* enc_w1 = (const float*)d_in[2];
  const float* enc_b1 = (const float*)d_in[3];
  const float* enc_w2 = (const float*)d_in[4];
  const float* enc_b2 = (const float*)d_in[5];
  const float* g1_wl = (const float*)d_in[6];
  const float* g1_wr = (const float*)d_in[7];
  const float* g1_we = (const float*)d_in[8];
  const float* g1_att = (const float*)d_in[9];
  const float* g1_b = (const float*)d_in[10];
  const float* bn1_g = (const float*)d_in[11];
  const float* bn1_b = (const float*)d_in[12];
  const float* g2_wl = (const float*)d_in[13];
  const float* g2_wr = (const float*)d_in[14];
  const float* g2_we = (const float*)d_in[15];
  const float* g2_att = (const float*)d_in[16];
  const float* g2_b = (const float*)d_in[17];
  const float* bn2_g = (const float*)d_in[18];
  const float* bn2_b = (const float*)d_in[19];
  const float* sage_wl = (const float*)d_in[20];
  const float* sage_bl = (const float*)d_in[21];
  const float* sage_wr = (const float*)d_in[22];
  const float* bn3_g = (const float*)d_in[23];
  const float* bn3_b = (const float*)d_in[24];
  const float* gh_w1 = (const float*)d_in[25];
  const float* gh_b1 = (const float*)d_in[26];
  const float* gh_w2 = (const float*)d_in[27];
  const float* gh_b2 = (const float*)d_in[28];
  const float* gh_w3 = (const float*)d_in[29];
  const float* gh_b3 = (const float*)d_in[30];
  const float* eh_w1 = (const float*)d_in[31];
  const float* eh_b1 = (const float*)d_in[32];
  const float* eh_w2 = (const float*)d_in[33];
  const float* eh_b2 = (const float*)d_in[34];
  const int* ei    = (const int*)d_in[35];
  const int* batch = (const int*)d_in[36];
  float* out = (float*)d_out;

  float* ws = (float*)d_ws;
  ushort* xlbf = (ushort*)(ws + OFF_XL);
  float* xr = ws + OFF_XR;
  ushort* h1bf = (ushort*)(ws + OFF_H1);
  ushort* wtl = (ushort*)(ws + OFF_WTL);
  ushort* wtr = (ushort*)(ws + OFF_WTR);
  float* h0 = ws + OFF_H0;   // later h2
  float* h3 = ws + OFF_H3;
  unsigned* cnt = (unsigned*)(ws + OFF_CNT);
  float* psum = ws + OFF_PSUM;
  float* pmax = ws + OFF_PMAX;
  float* pcnt = ws + OFF_PCNT;
  float* ea_csr = ws + OFF_EACSR;
  int* row_ptr = (int*)(ws + OFF_RP);
  int* srcs = (int*)(ws + OFF_SRC);
  int* bsums = (int*)(ws + OFF_BSUM);
  int* rank = (int*)(ws + OFF_XL);   // transient

  hipMemsetAsync(ws + OFF_ZERO, 0, ZERO_FLOATS * sizeof(float), stream);

  k_count<<<NE / 256, 256, 0, stream>>>(ei, cnt, rank);
  k_cast_wt<<<512, 256, 0, stream>>>(g2_wl, g2_wr, wtl, wtr);
  k_encoder<<<NN / (4 * ENC_NPW), 256, 0, stream>>>(x, enc_w1, enc_b1, enc_w2, enc_b2, h0);
  k_scan_blk<<<SCAN_NB, 256, 0, stream>>>(cnt, row_ptr, bsums);
  k_scan_add<<<SCAN_NB, 256, 0, stream>>>(bsums, row_ptr);
  k_csr_scatter<<<NE / 256, 256, 0, stream>>>(ei, rank, row_ptr, edge_attr, srcs, ea_csr);
  k_loop_row<<<(NN + 255) / 256, 256, 0, stream>>>(row_ptr, srcs, ea_csr);

  // ---- GAT layer 1 (fp32 vector GEMMs, K=64) ----
  k_gemm256<64, 1><<<NN / 32, 256, 0, stream>>>(h0, g1_wl, (void*)xlbf);
  k_gemm256<64, 0><<<NN / 32, 256, 0, stream>>>(h0, g1_wr, (void*)xr);
  k_gat_fused<1><<<NN / 4, 256, 0, stream>>>(xlbf, xr, g1_we, g1_att, srcs, ea_csr,
                                             row_ptr, g1_b, bn1_g, bn1_b, (void*)h1bf);

  // ---- GAT layer 2 (MFMA bf16 GEMMs, K=256) ----
  k_gemm_mfma<1><<<NN / 32, 256, 0, stream>>>(h1bf, wtl, (void*)xlbf);
  k_gemm_mfma<0><<<NN / 32, 256, 0, stream>>>(h1bf, wtr, (void*)xr);
  k_gat_fused<0><<<NN / 4, 256, 0, stream>>>(xlbf, xr, g2_we, g2_att, srcs, ea_csr,
                                             row_ptr, g2_b, bn2_g, bn2_b, (void*)h0);

  // ---- SAGE ----
  k_sage<<<NN / 4, 256, 0, stream>>>(h0, row_ptr, srcs, cnt, sage_wl, sage_bl, sage_wr, bn3_g, bn3_b, h3);

  // ---- pooling + heads ----
  k_pool<<<(NN + 255) / 256, 256, 0, stream>>>(h3, batch, psum, pmax, pcnt);
  k_graph_head<<<NG, 64, 0, stream>>>(psum, pmax, pcnt, gh_w1, gh_b1, gh_w2, gh_b2, gh_w3, gh_b3, out);
  k_edge_head<<<NE / 256, 256, 0, stream>>>(h3, ei, edge_attr, eh_w1, eh_b1, eh_w2, eh_b2, out + NG);
}